// Round 1
// baseline (631.566 us; speedup 1.0000x reference)
//
#include <hip/hip_runtime.h>
#include <hip/hip_bf16.h>
#include <math.h>

// ZoeDepth attractor layer, fused:
//   conv1(256->128) + ReLU + conv2(128->16) + softplus -> attractors (16/pixel)
//   bilinear(prev_bin 64x64 -> 128x128, align_corners) -> 64 bin centers/pixel
//   out = bc + sum_a dx/(1+300 dx^2), written twice (tuple of identical outputs)
//
// Block = 256 threads, owns 64 consecutive hw pixels of one batch (fixed h row).
// LDS: x tile [256c][64p] (+1 pad) staged once; 4 waves split 128 channels.

__global__ __launch_bounds__(256, 2)
void zoe_attractor_fused(const float* __restrict__ x,
                         const float* __restrict__ prev_bin,
                         const float* __restrict__ w1,
                         const float* __restrict__ b1,
                         const float* __restrict__ w2,
                         const float* __restrict__ b2,
                         float* __restrict__ out)
{
    __shared__ union {
        float xs[256][65];                 // 66560 B
        struct {
            float aL[4][16][64];           // conv2 partials per wave
            float att_s[16][64];           // final attractors
        } s2;                              // 20480 B
    } sm;

    const int tid = threadIdx.x;
    const int bid = blockIdx.x;
    const int b   = bid >> 8;              // batch
    const int t   = bid & 255;             // pixel tile
    const int hw0 = t << 6;                // first hw index of tile
    const int hrow = t >> 1;               // fixed output row
    const int w0   = (t & 1) << 6;         // column offset (0 or 64)

    // ---- stage x[b, :, tile] into LDS, coalesced float4 ----
    const float* xb = x + (size_t)b * 256 * 16384 + hw0;
    #pragma unroll
    for (int pass = 0; pass < 16; ++pass) {
        const int fi = pass * 256 + tid;
        const int c  = fi >> 4;
        const int pj = (fi & 15) << 2;
        const float4 v = *reinterpret_cast<const float4*>(xb + (size_t)c * 16384 + pj);
        sm.xs[c][pj + 0] = v.x;
        sm.xs[c][pj + 1] = v.y;
        sm.xs[c][pj + 2] = v.z;
        sm.xs[c][pj + 3] = v.w;
    }
    __syncthreads();

    // ---- conv1: each wave q computes m in [q*32, q*32+32) for its 64 pixels ----
    const int q = __builtin_amdgcn_readfirstlane(tid >> 6);   // wave id (uniform)
    const int p = tid & 63;                                   // pixel lane

    float h[32];
    {
        const float* b1q = b1 + q * 32;
        #pragma unroll
        for (int mi = 0; mi < 32; ++mi) h[mi] = b1q[mi];
    }

    const float* w1q = w1 + (size_t)(q * 32) * 256;
    for (int c4 = 0; c4 < 64; ++c4) {
        const float xv0 = sm.xs[c4 * 4 + 0][p];
        const float xv1 = sm.xs[c4 * 4 + 1][p];
        const float xv2 = sm.xs[c4 * 4 + 2][p];
        const float xv3 = sm.xs[c4 * 4 + 3][p];
        const float* w1c = w1q + c4 * 4;
        #pragma unroll
        for (int mi = 0; mi < 32; ++mi) {
            const float* wr = w1c + mi * 256;   // wave-uniform -> scalar loads
            h[mi] = fmaf(wr[0], xv0, h[mi]);
            h[mi] = fmaf(wr[1], xv1, h[mi]);
            h[mi] = fmaf(wr[2], xv2, h[mi]);
            h[mi] = fmaf(wr[3], xv3, h[mi]);
        }
    }

    // ---- ReLU + conv2 partials (16 attractors) ----
    #pragma unroll
    for (int mi = 0; mi < 32; ++mi) h[mi] = fmaxf(h[mi], 0.0f);

    float a[16];
    #pragma unroll
    for (int att = 0; att < 16; ++att) a[att] = 0.0f;
    {
        const float* w2q = w2 + q * 32;
        #pragma unroll
        for (int att = 0; att < 16; ++att) {
            const float* wr = w2q + (size_t)att * 128;   // wave-uniform
            #pragma unroll
            for (int mi = 0; mi < 32; ++mi)
                a[att] = fmaf(wr[mi], h[mi], a[att]);
        }
    }

    __syncthreads();   // xs region now dead; safe to alias with s2
    #pragma unroll
    for (int att = 0; att < 16; ++att) sm.s2.aL[q][att][p] = a[att];
    __syncthreads();

    // ---- reduce 4 waves, add bias, softplus -> att_s ----
    {
        const int p2 = tid & 63;
        const int ag = tid >> 6;
        #pragma unroll
        for (int k = 0; k < 4; ++k) {
            const int att = ag * 4 + k;
            float s = sm.s2.aL[0][att][p2] + sm.s2.aL[1][att][p2]
                    + sm.s2.aL[2][att][p2] + sm.s2.aL[3][att][p2];
            s += b2[att];
            const float sp = fmaxf(s, 0.0f) + log1pf(expf(-fabsf(s)));
            sm.s2.att_s[att][p2] = sp;
        }
    }
    __syncthreads();

    // ---- bilinear bin centers + attractor shifts + store (twice) ----
    const float scale = 63.0f / 127.0f;
    const float ysf = (float)hrow * scale;
    const int   y0  = (int)floorf(ysf);
    const float wy  = ysf - floorf(ysf);
    const int   y1  = (y0 + 1 < 63) ? (y0 + 1) : 63;
    const float omwy = 1.0f - wy;

    const float xf = (float)(w0 + p) * scale;
    const int   x0 = (int)floorf(xf);
    const float wx = xf - floorf(xf);
    const int   x1 = (x0 + 1 < 63) ? (x0 + 1) : 63;
    const float omwx = 1.0f - wx;

    const int jbase = tid >> 6;                         // wave id -> j stripe
    const float* pvb = prev_bin + (size_t)b * 64 * 4096;
    float* ob = out + (size_t)b * 64 * 16384 + hw0;
    const size_t out2_off = (size_t)8 * 64 * 16384;     // second tuple element

    #pragma unroll 4
    for (int jj = 0; jj < 16; ++jj) {
        const int j = jbase + jj * 4;
        const float* pv = pvb + (size_t)j * 4096;
        const float v00 = pv[y0 * 64 + x0];
        const float v01 = pv[y1 * 64 + x0];
        const float v10 = pv[y0 * 64 + x1];
        const float v11 = pv[y1 * 64 + x1];
        const float t0 = v00 * omwy + v01 * wy;
        const float t1 = v10 * omwy + v11 * wy;
        const float bc = t0 * omwx + t1 * wx;

        float delta = 0.0f;
        #pragma unroll
        for (int att = 0; att < 16; ++att) {
            const float dx  = sm.s2.att_s[att][p] - bc;
            const float den = fmaf(300.0f * dx, dx, 1.0f);
            delta += dx * __builtin_amdgcn_rcpf(den);
        }
        const float ov = bc + delta;
        const size_t oi = (size_t)j * 16384 + p;
        ob[oi] = ov;
        ob[oi + out2_off] = ov;
    }
}

extern "C" void kernel_launch(void* const* d_in, const int* in_sizes, int n_in,
                              void* d_out, int out_size, void* d_ws, size_t ws_size,
                              hipStream_t stream) {
    const float* x        = (const float*)d_in[0];
    const float* prev_bin = (const float*)d_in[1];
    const float* w1       = (const float*)d_in[2];
    const float* b1       = (const float*)d_in[3];
    const float* w2       = (const float*)d_in[4];
    const float* b2       = (const float*)d_in[5];
    float* out = (float*)d_out;

    dim3 grid(2048), block(256);
    hipLaunchKernelGGL(zoe_attractor_fused, grid, block, 0, stream,
                       x, prev_bin, w1, b1, w2, b2, out);
}

// Round 14
// 373.165 us; speedup vs baseline: 1.6925x; 1.6925x over previous
//
#include <hip/hip_runtime.h>
#include <hip/hip_bf16.h>
#include <math.h>

// ZoeDepth attractor layer, fused, v2 (resubmit #12 after broker timeouts):
//   conv1 as register-blocked GEMM (8m x 4p per thread), w1 bf16 in LDS [m][k],
//   x f32 in LDS [k][p], k-chunked x4. conv2 + softplus + bilinear + attractor
//   epilogue fused. 512 threads/block, block = 128m x 128p (one output row).
// No scalar loads in the hot loop; everything vector from LDS.

__device__ __forceinline__ unsigned short f2bf(float f) {
    unsigned int u = __float_as_uint(f);
    u += 0x7fffu + ((u >> 16) & 1u);    // round-to-nearest-even
    return (unsigned short)(u >> 16);
}

__global__ __launch_bounds__(512, 4)
void zoe_attractor_fused2(const float* __restrict__ x,
                          const float* __restrict__ prev_bin,
                          const float* __restrict__ w1,
                          const float* __restrict__ b1,
                          const float* __restrict__ w2,
                          const float* __restrict__ b2,
                          float* __restrict__ out)
{
    __shared__ union {
        struct {
            float xs[64][132];            // [k][p] f32, 33792 B (pad 4 -> row 528B)
            unsigned short ws[128][72];   // [m][k] bf16 bits, 18432 B (row 144B)
        } c1;                             // 52224 B
        struct {
            float hs[128][132];           // [p][m] f32, 67584 B
            float as[16][128];            // 8192 B
        } c2;                             // 75776 B
    } sm;

    const int tid = threadIdx.x;
    const int bid = blockIdx.x;
    const int b    = bid >> 7;            // batch
    const int hrow = bid & 127;           // output row

    const int wave = tid >> 6;
    const int lane = tid & 63;
    const int wm = wave >> 1;             // 0..3 : m-group of 32
    const int wp = wave & 1;              // 0..1 : p-half of 64
    const int ml = lane >> 4;             // 0..3 : m-sub of 8
    const int pl = lane & 15;             // 0..15: p-sub of 4
    const int m0 = wm * 32 + ml * 8;
    const int p0 = wp * 64 + pl * 4;

    float acc[8][4];
    #pragma unroll
    for (int i = 0; i < 8; ++i)
        #pragma unroll
        for (int j = 0; j < 4; ++j) acc[i][j] = 0.0f;

    const float* xb = x + (size_t)b * 256 * 16384 + hrow * 128;

    for (int t = 0; t < 4; ++t) {
        // ---- stage x chunk [64k][128p] f32, coalesced float4 ----
        #pragma unroll
        for (int pass = 0; pass < 4; ++pass) {
            const int i  = pass * 512 + tid;
            const int k  = i >> 5;
            const int p4 = (i & 31) << 2;
            const float4 v = *reinterpret_cast<const float4*>(
                xb + (size_t)(t * 64 + k) * 16384 + p4);
            *reinterpret_cast<float4*>(&sm.c1.xs[k][p4]) = v;
        }
        // ---- stage w1 chunk [128m][64k] -> bf16, coalesced ----
        #pragma unroll
        for (int pass = 0; pass < 4; ++pass) {
            const int i  = pass * 512 + tid;
            const int m  = i >> 4;
            const int c4 = (i & 15) << 2;
            const float4 v = *reinterpret_cast<const float4*>(
                w1 + (size_t)m * 256 + t * 64 + c4);
            uint2 dd;
            dd.x = (unsigned int)f2bf(v.x) | ((unsigned int)f2bf(v.y) << 16);
            dd.y = (unsigned int)f2bf(v.z) | ((unsigned int)f2bf(v.w) << 16);
            *reinterpret_cast<uint2*>(&sm.c1.ws[m][c4]) = dd;
        }
        __syncthreads();

        // ---- compute: 16 groups of 4 k ----
        for (int g = 0; g < 16; ++g) {
            uint2 wreg[8];
            #pragma unroll
            for (int mm = 0; mm < 8; ++mm)
                wreg[mm] = *reinterpret_cast<const uint2*>(&sm.c1.ws[m0 + mm][g * 4]);
            #pragma unroll
            for (int kk = 0; kk < 4; ++kk) {
                const float4 xv = *reinterpret_cast<const float4*>(
                    &sm.c1.xs[g * 4 + kk][p0]);
                #pragma unroll
                for (int mm = 0; mm < 8; ++mm) {
                    const unsigned int d = (kk < 2) ? wreg[mm].x : wreg[mm].y;
                    const float wv = (kk & 1)
                        ? __uint_as_float(d & 0xffff0000u)
                        : __uint_as_float(d << 16);
                    acc[mm][0] = fmaf(wv, xv.x, acc[mm][0]);
                    acc[mm][1] = fmaf(wv, xv.y, acc[mm][1]);
                    acc[mm][2] = fmaf(wv, xv.z, acc[mm][2]);
                    acc[mm][3] = fmaf(wv, xv.w, acc[mm][3]);
                }
            }
        }
        __syncthreads();
    }

    // ---- bias + ReLU, exchange h via LDS [p][m] f32 ----
    float b1v[8];
    #pragma unroll
    for (int mm = 0; mm < 8; ++mm) b1v[mm] = b1[m0 + mm];

    #pragma unroll
    for (int pp = 0; pp < 4; ++pp) {
        float4 ha, hb;
        ha.x = fmaxf(acc[0][pp] + b1v[0], 0.0f);
        ha.y = fmaxf(acc[1][pp] + b1v[1], 0.0f);
        ha.z = fmaxf(acc[2][pp] + b1v[2], 0.0f);
        ha.w = fmaxf(acc[3][pp] + b1v[3], 0.0f);
        hb.x = fmaxf(acc[4][pp] + b1v[4], 0.0f);
        hb.y = fmaxf(acc[5][pp] + b1v[5], 0.0f);
        hb.z = fmaxf(acc[6][pp] + b1v[6], 0.0f);
        hb.w = fmaxf(acc[7][pp] + b1v[7], 0.0f);
        *reinterpret_cast<float4*>(&sm.c2.hs[p0 + pp][m0])     = ha;
        *reinterpret_cast<float4*>(&sm.c2.hs[p0 + pp][m0 + 4]) = hb;
    }
    __syncthreads();

    // ---- conv2: each thread 1 pixel x 4 attractors; w2 scalar (sL1-hot) ----
    const int p  = tid & 127;
    const int ag = tid >> 7;              // 0..3, uniform per 2-wave group
    float a[4] = {0.0f, 0.0f, 0.0f, 0.0f};
    #pragma unroll 4
    for (int mc = 0; mc < 32; ++mc) {
        const float4 hv = *reinterpret_cast<const float4*>(&sm.c2.hs[p][mc * 4]);
        #pragma unroll
        for (int aa = 0; aa < 4; ++aa) {
            const float* wr = w2 + (size_t)(ag * 4 + aa) * 128 + mc * 4; // uniform
            a[aa] = fmaf(wr[0], hv.x, a[aa]);
            a[aa] = fmaf(wr[1], hv.y, a[aa]);
            a[aa] = fmaf(wr[2], hv.z, a[aa]);
            a[aa] = fmaf(wr[3], hv.w, a[aa]);
        }
    }
    #pragma unroll
    for (int aa = 0; aa < 4; ++aa) {
        const int att = ag * 4 + aa;
        const float s = a[aa] + b2[att];
        sm.c2.as[att][p] = fmaxf(s, 0.0f) + log1pf(expf(-fabsf(s)));
    }
    __syncthreads();

    // ---- bilinear bin centers + attractor shifts + store (twice) ----
    const float scale = 63.0f / 127.0f;
    const float ysf = (float)hrow * scale;
    const int   y0  = (int)ysf;
    const float wy  = ysf - (float)y0;
    const int   y1  = (y0 + 1 < 63) ? (y0 + 1) : 63;
    const float omwy = 1.0f - wy;

    const float xf = (float)p * scale;
    const int   x0 = (int)xf;
    const float wx = xf - (float)x0;
    const int   x1 = (x0 + 1 < 63) ? (x0 + 1) : 63;
    const float omwx = 1.0f - wx;

    const float* pvb = prev_bin + (size_t)b * 64 * 4096;
    float* ob = out + (size_t)b * 64 * 16384 + hrow * 128;
    const size_t out2_off = (size_t)8 * 64 * 16384;

    #pragma unroll 4
    for (int jj = 0; jj < 16; ++jj) {
        const int j = ag + jj * 4;
        const float* pv = pvb + (size_t)j * 4096;
        const float v00 = pv[y0 * 64 + x0];
        const float v01 = pv[y1 * 64 + x0];
        const float v10 = pv[y0 * 64 + x1];
        const float v11 = pv[y1 * 64 + x1];
        const float t0 = v00 * omwy + v01 * wy;
        const float t1 = v10 * omwy + v11 * wy;
        const float bc = t0 * omwx + t1 * wx;

        float delta = 0.0f;
        #pragma unroll
        for (int att = 0; att < 16; ++att) {
            const float dx  = sm.c2.as[att][p] - bc;
            const float den = fmaf(300.0f * dx, dx, 1.0f);
            delta += dx * __builtin_amdgcn_rcpf(den);
        }
        const float ov = bc + delta;
        const size_t oi = (size_t)j * 16384 + p;
        ob[oi] = ov;
        ob[oi + out2_off] = ov;
    }
}

extern "C" void kernel_launch(void* const* d_in, const int* in_sizes, int n_in,
                              void* d_out, int out_size, void* d_ws, size_t ws_size,
                              hipStream_t stream) {
    const float* x        = (const float*)d_in[0];
    const float* prev_bin = (const float*)d_in[1];
    const float* w1       = (const float*)d_in[2];
    const float* b1       = (const float*)d_in[3];
    const float* w2       = (const float*)d_in[4];
    const float* b2       = (const float*)d_in[5];
    float* out = (float*)d_out;

    dim3 grid(1024), block(512);
    hipLaunchKernelGGL(zoe_attractor_fused2, grid, block, 0, stream,
                       x, prev_bin, w1, b1, w2, b2, out);
}